// Round 7
// baseline (839.708 us; speedup 1.0000x reference)
//
#include <hip/hip_runtime.h>
#include <stdint.h>

typedef unsigned short u16;
typedef float f32x4 __attribute__((ext_vector_type(4)));
typedef float f32x16 __attribute__((ext_vector_type(16)));
typedef __bf16 v8bf __attribute__((ext_vector_type(8)));

static __device__ __forceinline__ float bf2f(u16 u) {
  union { uint32_t i; float f; } v; v.i = ((uint32_t)u) << 16; return v.f;
}
static __device__ __forceinline__ u16 f2bf(float f) {
  union { float f; uint32_t i; } v; v.f = f;
  uint32_t b = v.i;
  return (u16)((b + 0x7FFFu + ((b >> 16) & 1u)) >> 16);
}

// ---------------- K1: LayerNorm over C=96 (fp32 in) -> bf16 xn ----------------
__global__ __launch_bounds__(256) void k_ln(const float* __restrict__ x,
                                            const float* __restrict__ gamma,
                                            const float* __restrict__ beta,
                                            u16* __restrict__ xn) {
  int tid = threadIdx.x;
  int vox = blockIdx.x * 64 + (tid >> 2);
  int q = tid & 3;
  const float4* px = (const float4*)(x + (size_t)vox * 96 + q * 24);
  float f[24];
  *(float4*)&f[0]  = px[0]; *(float4*)&f[4]  = px[1]; *(float4*)&f[8]  = px[2];
  *(float4*)&f[12] = px[3]; *(float4*)&f[16] = px[4]; *(float4*)&f[20] = px[5];
  float s = 0.f, s2 = 0.f;
#pragma unroll
  for (int i = 0; i < 24; ++i) { s += f[i]; s2 += f[i] * f[i]; }
  s += __shfl_xor(s, 1);  s += __shfl_xor(s, 2);
  s2 += __shfl_xor(s2, 1); s2 += __shfl_xor(s2, 2);
  float mu = s * (1.f / 96.f);
  float var = s2 * (1.f / 96.f) - mu * mu;
  float rs = rsqrtf(var + 1e-5f);
  uint32_t ow[12];
#pragma unroll
  for (int i = 0; i < 12; ++i) {
    int c0 = q * 24 + 2 * i;
    float v0 = (f[2 * i]     - mu) * rs * gamma[c0]     + beta[c0];
    float v1 = (f[2 * i + 1] - mu) * rs * gamma[c0 + 1] + beta[c0 + 1];
    ow[i] = (uint32_t)f2bf(v0) | ((uint32_t)f2bf(v1) << 16);
  }
  uint4* po = (uint4*)(xn + (size_t)vox * 96 + q * 24);
  po[0] = *(uint4*)&ow[0]; po[1] = *(uint4*)&ow[4]; po[2] = *(uint4*)&ow[8];
}

// ---------------- K2: repack qkv_w (fp32) into bf16 MFMA B-fragment layout ----------------
// Wb[tap][ks][nt][lane][j] : value = W[tap][ci=ks*32+(lane>>4)*8+j][co=nt*16+(lane&15)]
__global__ __launch_bounds__(256) void k_repack(const float* __restrict__ qw,
                                                u16* __restrict__ Wb) {
  int t = blockIdx.x * 256 + threadIdx.x;
  if (t >= 27 * 3 * 18 * 64) return;
  int l = t & 63;
  int rest = t >> 6;
  int nt = rest % 18;
  int ks = (rest / 18) % 3;
  int tap = rest / 54;
  int co = nt * 16 + (l & 15);
  int cibase = ks * 32 + (l >> 4) * 8;
  u16 vals[8];
#pragma unroll
  for (int j = 0; j < 8; ++j)
    vals[j] = f2bf(qw[((size_t)tap * 96 + cibase + j) * 288 + co]);
  *(uint4*)(Wb + (size_t)t * 8) = *(uint4*)vals;
}

// ---------------- K3: conv3d 3x3x3 96->288 via MFMA bf16 ----------------
// Block = TWO adjacent z-columns (128 rows), 4 waves; wave = 1 column x 144 cols.
// A: double-buffered LDS, staged direct global->LDS once per dxy (R5 macro —
// no lambda/array staging: that spilled to scratch in R6, +244 MB traffic).
// B: register DOUBLE-buffer bc[9]/bn[9]: all 9 next-t loads issued BEFORE the
// 36 MFMAs of t -> each B load gets a full t-step (~180+ cyc) of cover.
__global__ __launch_bounds__(256, 2) void k_conv(const u16* __restrict__ xn,
                                                 const u16* __restrict__ Wb,
                                                 const float* __restrict__ qkvb,
                                                 u16* __restrict__ y) {
  __shared__ u16 As[2][2 * 66 * 104];  // 54,912 B; pitch 104 (2-way benign)
  int tid = threadIdx.x;
  // bijective XCD swizzle: 2048 blocks, 8 XCDs, 256 blocks/XCD.
  int bid = blockIdx.x;
  int swz = (bid & 7) * 256 + (bid >> 3);
  int x0 = swz >> 5;
  int y0 = (swz & 31) * 2;
  int lane = tid & 63, w = tid >> 6;
  int wcol = w >> 1, wc = w & 1;

  f32x4 acc[4][9];
#pragma unroll
  for (int m = 0; m < 4; ++m)
#pragma unroll
    for (int n = 0; n < 9; ++n) acc[m][n] = (f32x4)0.f;

  const u16* wbase = Wb + (size_t)(wc * 9) * 512 + (size_t)lane * 8;

#define STAGE_A(DXY, BUF)                                                      \
  {                                                                            \
    int dx_ = (DXY) / 3, dy_ = (DXY) % 3;                                      \
    int xx_ = x0 + dx_ - 1;                                                    \
    for (int i = tid; i < 2 * 66 * 12; i += 256) {                             \
      int c_ = i / 792, rem_ = i - c_ * 792;                                   \
      int row_ = rem_ / 12, c8_ = rem_ - row_ * 12;                            \
      int yy_ = y0 + c_ + dy_ - 1;                                             \
      uint4 v_ = make_uint4(0u, 0u, 0u, 0u);                                   \
      if (((unsigned)xx_ < 64u) && ((unsigned)yy_ < 64u) && row_ >= 1 &&       \
          row_ <= 64) {                                                        \
        const uint4* src_ = (const uint4*)(xn + ((size_t)(xx_ * 64 + yy_) * 64) * 96); \
        v_ = src_[(row_ - 1) * 12 + c8_];                                      \
      }                                                                        \
      *(uint4*)&As[BUF][(c_ * 66 + row_) * 104 + c8_ * 8] = v_;                \
    }                                                                          \
  }

  STAGE_A(0, 0);
  __syncthreads();

  // preload B for (dxy=0, t=0)
  v8bf bc[9];
#pragma unroll
  for (int nt = 0; nt < 9; ++nt)
    bc[nt] = *(const v8bf*)(wbase + (size_t)nt * 512);

  for (int dxy = 0; dxy < 9; ++dxy) {
    const u16* Ab = &As[dxy & 1][0];
    const u16* base2 = wbase + (size_t)dxy * 9 * 9216;
    bool last_dxy = (dxy == 8);

#pragma unroll
    for (int t = 0; t < 9; ++t) {
      int dz = t / 3, ks = t - dz * 3;
      int ar = (lane & 15) + dz;
      int ac = ks * 32 + (lane >> 4) * 8;
      const u16* abase = &Ab[(wcol * 66 + ar) * 104 + ac];
      v8bf a0 = *(const v8bf*)(abase);
      v8bf a1 = *(const v8bf*)(abase + 16 * 104);
      v8bf a2 = *(const v8bf*)(abase + 32 * 104);
      v8bf a3 = *(const v8bf*)(abase + 48 * 104);
      // issue ALL next-t B loads before this t's MFMA block
      const u16* bnxt = base2 + (size_t)(t + 1) * 9216;
      bool more = (t < 8) || !last_dxy;
      v8bf bn[9];
      if (more) {
#pragma unroll
        for (int nt = 0; nt < 9; ++nt)
          bn[nt] = *(const v8bf*)(bnxt + (size_t)nt * 512);
      }
      __builtin_amdgcn_s_setprio(1);
#pragma unroll
      for (int nt = 0; nt < 9; ++nt) {
        v8bf bb = bc[nt];
        acc[0][nt] = __builtin_amdgcn_mfma_f32_16x16x32_bf16(a0, bb, acc[0][nt], 0, 0, 0);
        acc[1][nt] = __builtin_amdgcn_mfma_f32_16x16x32_bf16(a1, bb, acc[1][nt], 0, 0, 0);
        acc[2][nt] = __builtin_amdgcn_mfma_f32_16x16x32_bf16(a2, bb, acc[2][nt], 0, 0, 0);
        acc[3][nt] = __builtin_amdgcn_mfma_f32_16x16x32_bf16(a3, bb, acc[3][nt], 0, 0, 0);
      }
      __builtin_amdgcn_s_setprio(0);
      if (more) {
#pragma unroll
        for (int nt = 0; nt < 9; ++nt) bc[nt] = bn[nt];
      }
    }

    if (!last_dxy) STAGE_A(dxy + 1, (dxy + 1) & 1);
    __syncthreads();
  }
#undef STAGE_A

  size_t voxbase = ((size_t)x0 * 64 + (y0 + wcol)) * 64;
#pragma unroll
  for (int m = 0; m < 4; ++m)
#pragma unroll
    for (int nt = 0; nt < 9; ++nt) {
      int co = wc * 144 + nt * 16 + (lane & 15);
      float bias = qkvb[co];
#pragma unroll
      for (int r = 0; r < 4; ++r) {
        int vrow = m * 16 + (lane >> 4) * 4 + r;
        y[(voxbase + vrow) * 288 + co] = f2bf(acc[m][nt][r] + bias);
      }
    }
}

// ---------------- K4: Gram via MFMA 32x32x16 ----------------
// S[f,h,c,d] = sum_g q.k ; qn2/kn2 = diagonals of QQ/KK Grams (free: for
// 32x32x16, A-frag(row=l&31,k=(l>>5)*8+j) and B-frag(col=l&31,k=...) have
// IDENTICAL register layouts when indexing (channel, g) -> QQ=mfma(aq,aq).
__global__ __launch_bounds__(256) void k_gram2(const u16* __restrict__ y,
                                               float* __restrict__ S_part,
                                               float* __restrict__ qn_part,
                                               float* __restrict__ kn_part) {
  __shared__ u16 buf[2][16 * 292];
  int tid = threadIdx.x;
  int f = blockIdx.x >> 4, chunk = blockIdx.x & 15;
  int fx = f >> 4, fy = (f >> 2) & 3, fz = f & 3;
  int l = tid & 63, h = tid >> 6;

  f32x16 aqk = (f32x16)0.f, aqq = (f32x16)0.f, akk = (f32x16)0.f;

  int i0 = tid;
  int gl0 = i0 / 24, c80 = i0 - gl0 * 24;
  int c00 = c80 * 8;
  int dst0 = (c00 < 96) ? ((c00 / 24) * 32 + (c00 % 24))
                        : (128 + ((c00 - 96) / 24) * 32 + ((c00 - 96) % 24));
  int i1 = tid + 256;
  int gl1 = i1 / 24, c81 = i1 - gl1 * 24;
  int c01 = c81 * 8;
  int dst1 = (c01 < 96) ? ((c01 / 24) * 32 + (c01 % 24))
                        : (128 + ((c01 - 96) / 24) * 32 + ((c01 - 96) % 24));
  bool has1 = (tid < 128);

  uint4 s0, s1;
  auto gload = [&](int sub) {
    int gbase = chunk * 256 + sub * 16;
    {
      int g = gbase + gl0;
      int gx = g >> 8, gy = (g >> 4) & 15, gz = g & 15;
      size_t vox = ((size_t)(gx * 4 + fx) * 64 + (gy * 4 + fy)) * 64 + (gz * 4 + fz);
      s0 = *(const uint4*)(y + vox * 288 + c00);
    }
    if (has1) {
      int g = gbase + gl1;
      int gx = g >> 8, gy = (g >> 4) & 15, gz = g & 15;
      size_t vox = ((size_t)(gx * 4 + fx) * 64 + (gy * 4 + fy)) * 64 + (gz * 4 + fz);
      s1 = *(const uint4*)(y + vox * 288 + c01);
    }
  };
  auto gwrite = [&](int bufi) {
    u16* p0 = &buf[bufi][gl0 * 292 + dst0];
    *(uint2*)p0 = make_uint2(s0.x, s0.y);
    *(uint2*)(p0 + 4) = make_uint2(s0.z, s0.w);
    if (has1) {
      u16* p1 = &buf[bufi][gl1 * 292 + dst1];
      *(uint2*)p1 = make_uint2(s1.x, s1.y);
      *(uint2*)(p1 + 4) = make_uint2(s1.z, s1.w);
    }
  };

  gload(0);
  gwrite(0);
  __syncthreads();

  for (int sub = 0; sub < 16; ++sub) {
    if (sub < 15) gload(sub + 1);  // issue next-tile loads early
    const u16* bb = &buf[sub & 1][(l >> 5) * 8 * 292 + h * 32 + (l & 31)];
    v8bf aq, ak;
#pragma unroll
    for (int j = 0; j < 8; ++j) {
      ((u16*)&aq)[j] = bb[j * 292];
      ((u16*)&ak)[j] = bb[j * 292 + 128];
    }
    aqk = __builtin_amdgcn_mfma_f32_32x32x16_bf16(aq, ak, aqk, 0, 0, 0);
    aqq = __builtin_amdgcn_mfma_f32_32x32x16_bf16(aq, aq, aqq, 0, 0, 0);
    akk = __builtin_amdgcn_mfma_f32_32x32x16_bf16(ak, ak, akk, 0, 0, 0);
    if (sub < 15) gwrite((sub + 1) & 1);
    __syncthreads();
  }

  int col = l & 31, hi = l >> 5;
  if (col < 24) {
    float* Sp = S_part + (((size_t)(chunk * 64 + f)) * 4 + h) * 576;
#pragma unroll
    for (int reg = 0; reg < 12; ++reg) {
      int row = (reg & 3) + 8 * (reg >> 2) + 4 * hi;
      Sp[row * 24 + col] = aqk[reg];
    }
    int sel = (col & 7) - 4 * hi;
    if (sel >= 0 && sel < 4) {
      int dreg = (col >> 3) * 4 + sel;
      float qn = 0.f, kn = 0.f;
#pragma unroll
      for (int r = 0; r < 12; ++r)
        if (r == dreg) { qn = aqq[r]; kn = akk[r]; }
      qn_part[((size_t)(chunk * 64 + f)) * 96 + h * 24 + col] = qn;
      kn_part[((size_t)(chunk * 64 + f)) * 96 + h * 24 + col] = kn;
    }
  }
}

// ---------------- K5: sum partials + normalize + softmax + fold out_w -> Mt ----------------
__global__ __launch_bounds__(256) void k_attn(const float* __restrict__ S_part,
                                              const float* __restrict__ qn_part,
                                              const float* __restrict__ kn_part,
                                              const float* __restrict__ out_w,
                                              const float* __restrict__ temp,
                                              u16* __restrict__ Mt) {
  __shared__ float Ssum[2304];
  __shared__ float attn[2304];
  __shared__ float invq[96], invk[96];
  __shared__ float ow[9216];
  int tid = threadIdx.x;
  int f = blockIdx.x;
  for (int o = tid; o < 2304; o += 256) {
    float s = 0.f;
#pragma unroll
    for (int c = 0; c < 16; ++c) s += S_part[((size_t)(c * 64 + f)) * 2304 + o];
    Ssum[o] = s;
  }
  if (tid < 96) {
    float qn = 0.f, kn = 0.f;
#pragma unroll
    for (int c = 0; c < 16; ++c) {
      qn += qn_part[((size_t)(c * 64 + f)) * 96 + tid];
      kn += kn_part[((size_t)(c * 64 + f)) * 96 + tid];
    }
    invq[tid] = 1.f / fmaxf(sqrtf(qn), 1e-12f);
    invk[tid] = 1.f / fmaxf(sqrtf(kn), 1e-12f);
  }
  for (int i = tid; i < 9216; i += 256) ow[i] = out_w[i];
  __syncthreads();
  if (tid < 96) {
    int h = tid / 24, c = tid % 24;
    float tmp = temp[h];
    const float* Sr = &Ssum[h * 576 + c * 24];
    float lg[24];
    float mx = -1e30f;
#pragma unroll
    for (int d = 0; d < 24; ++d) {
      lg[d] = Sr[d] * invq[tid] * invk[h * 24 + d] * tmp;
      mx = fmaxf(mx, lg[d]);
    }
    float sum = 0.f;
#pragma unroll
    for (int d = 0; d < 24; ++d) { lg[d] = __expf(lg[d] - mx); sum += lg[d]; }
    float inv = 1.f / sum;
#pragma unroll
    for (int d = 0; d < 24; ++d) attn[h * 576 + c * 24 + d] = lg[d] * inv;
  }
  __syncthreads();
  for (int o = tid; o < 9216; o += 256) {
    int j = o / 96, cp = o - j * 96;
    int h2 = j / 24, d = j % 24;
    float s = 0.f;
#pragma unroll
    for (int cc = 0; cc < 24; ++cc)
      s += attn[h2 * 576 + cc * 24 + d] * ow[cp * 96 + h2 * 24 + cc];
    Mt[(size_t)f * 9216 + o] = f2bf(s);
  }
}

// ---------------- K6: out = Mt[f] @ v + out_b + x (residual), fp32 out ----------------
__global__ __launch_bounds__(256, 1) void k_final(const u16* __restrict__ y,
                                                  const u16* __restrict__ Mt,
                                                  const float* __restrict__ xin,
                                                  const float* __restrict__ out_b,
                                                  float* __restrict__ out) {
  __shared__ u16 mt4[4 * 9216];  // 73728 B: Mt for fz=0..3
  __shared__ u16 vst[64 * 96];   // 12288 B: one column's v
  int tid = threadIdx.x;
  int b = blockIdx.x;
  int fxy = b >> 4, chunk = b & 15;
  int fx = fxy >> 2, fy = fxy & 3;
  int x = fx + 4 * chunk;
  const uint4* msrc = (const uint4*)(Mt + (size_t)(fx * 16 + fy * 4) * 9216);
  for (int i = tid; i < 4608; i += 256) ((uint4*)mt4)[i] = msrc[i];
  int vox = tid >> 2, qo = tid & 3, fz = vox & 3;
  float ob[24];
#pragma unroll
  for (int cc = 0; cc < 24; ++cc) ob[cc] = out_b[qo * 24 + cc];

  for (int m = 0; m < 16; ++m) {
    int yy = fy + 4 * m;
    size_t colvox = ((size_t)x * 64 + yy) * 64;
    __syncthreads();
    for (int i = tid; i < 768; i += 256) {
      int vv = i / 12, c8 = i - vv * 12;
      ((uint4*)vst)[vv * 12 + c8] =
          *(const uint4*)(y + (colvox + vv) * 288 + 192 + c8 * 8);
    }
    __syncthreads();
    float acc[24];
#pragma unroll
    for (int cc = 0; cc < 24; ++cc) acc[cc] = ob[cc];
    const u16* mslice = &mt4[fz * 9216 + qo * 24];
#pragma unroll 4
    for (int j = 0; j < 96; ++j) {
      float vj = bf2f(vst[vox * 96 + j]);
      const uint4* mq = (const uint4*)(mslice + j * 96);
      uint4 m0 = mq[0], m1 = mq[1], m2 = mq[2];
      uint32_t mw[12];
      *(uint4*)&mw[0] = m0; *(uint4*)&mw[4] = m1; *(uint4*)&mw[8] = m2;
#pragma unroll
      for (int i2 = 0; i2 < 12; ++i2) {
        union { uint32_t u; float f; } lo, hi;
        lo.u = mw[i2] << 16; hi.u = mw[i2] & 0xFFFF0000u;
        acc[2 * i2] += vj * lo.f;
        acc[2 * i2 + 1] += vj * hi.f;
      }
    }
    const float4* xs = (const float4*)(xin + (colvox + vox) * 96 + qo * 24);
    float4* op = (float4*)(out + (colvox + vox) * 96 + qo * 24);
#pragma unroll
    for (int i2 = 0; i2 < 6; ++i2) {
      float4 xv = xs[i2];
      float4 r;
      r.x = acc[4 * i2 + 0] + xv.x;
      r.y = acc[4 * i2 + 1] + xv.y;
      r.z = acc[4 * i2 + 2] + xv.z;
      r.w = acc[4 * i2 + 3] + xv.w;
      op[i2] = r;
    }
  }
}

extern "C" void kernel_launch(void* const* d_in, const int* in_sizes, int n_in,
                              void* d_out, int out_size, void* d_ws, size_t ws_size,
                              hipStream_t stream) {
  const float* x  = (const float*)d_in[0];
  const float* g  = (const float*)d_in[1];
  const float* be = (const float*)d_in[2];
  const float* qw = (const float*)d_in[3];
  const float* qb = (const float*)d_in[4];
  const float* ow = (const float*)d_in[5];
  const float* ob = (const float*)d_in[6];
  const float* tp = (const float*)d_in[7];
  float* out = (float*)d_out;

  // d_out (100.7 MB) doubles as scratch until k_final overwrites it:
  //   xn (bf16, 50.3 MB) dead after k_conv; S/qn/kn partials dead after k_attn.
  u16* xn = (u16*)d_out;
  float* S_part  = (float*)((char*)d_out + 50331648);  // 9,437,184 B
  float* qn_part = (float*)((char*)d_out + 59768832);  //   393,216 B
  float* kn_part = (float*)((char*)d_out + 60162048);  //   393,216 B

  char* w = (char*)d_ws;
  u16* y  = (u16*)(w);                 // 150,994,944 B
  u16* Wb = (u16*)(w + 150994944);     //   1,492,992 B
  u16* Mt = (u16*)(w + 152487936);     //   1,179,648 B (end ~153.7 MB)

  hipLaunchKernelGGL(k_ln, dim3(4096), dim3(256), 0, stream, x, g, be, xn);
  hipLaunchKernelGGL(k_repack, dim3((27 * 3 * 18 * 64 + 255) / 256), dim3(256), 0, stream, qw, Wb);
  hipLaunchKernelGGL(k_conv, dim3(2048), dim3(256), 0, stream, xn, Wb, qb, y);
  hipLaunchKernelGGL(k_gram2, dim3(1024), dim3(256), 0, stream, y, S_part, qn_part, kn_part);
  hipLaunchKernelGGL(k_attn, dim3(64), dim3(256), 0, stream, S_part, qn_part, kn_part, ow, tp, Mt);
  hipLaunchKernelGGL(k_final, dim3(256), dim3(256), 0, stream, y, Mt, x, ob, out);
}

// Round 8
// 476.766 us; speedup vs baseline: 1.7613x; 1.7613x over previous
//
#include <hip/hip_runtime.h>
#include <stdint.h>

typedef unsigned short u16;
typedef float f32x4 __attribute__((ext_vector_type(4)));
typedef float f32x16 __attribute__((ext_vector_type(16)));
typedef __bf16 v8bf __attribute__((ext_vector_type(8)));

static __device__ __forceinline__ float bf2f(u16 u) {
  union { uint32_t i; float f; } v; v.i = ((uint32_t)u) << 16; return v.f;
}
static __device__ __forceinline__ u16 f2bf(float f) {
  union { float f; uint32_t i; } v; v.f = f;
  uint32_t b = v.i;
  return (u16)((b + 0x7FFFu + ((b >> 16) & 1u)) >> 16);
}

// ---------------- K1: LayerNorm over C=96 (fp32 in) -> bf16 xn ----------------
__global__ __launch_bounds__(256) void k_ln(const float* __restrict__ x,
                                            const float* __restrict__ gamma,
                                            const float* __restrict__ beta,
                                            u16* __restrict__ xn) {
  int tid = threadIdx.x;
  int vox = blockIdx.x * 64 + (tid >> 2);
  int q = tid & 3;
  const float4* px = (const float4*)(x + (size_t)vox * 96 + q * 24);
  float f[24];
  *(float4*)&f[0]  = px[0]; *(float4*)&f[4]  = px[1]; *(float4*)&f[8]  = px[2];
  *(float4*)&f[12] = px[3]; *(float4*)&f[16] = px[4]; *(float4*)&f[20] = px[5];
  float s = 0.f, s2 = 0.f;
#pragma unroll
  for (int i = 0; i < 24; ++i) { s += f[i]; s2 += f[i] * f[i]; }
  s += __shfl_xor(s, 1);  s += __shfl_xor(s, 2);
  s2 += __shfl_xor(s2, 1); s2 += __shfl_xor(s2, 2);
  float mu = s * (1.f / 96.f);
  float var = s2 * (1.f / 96.f) - mu * mu;
  float rs = rsqrtf(var + 1e-5f);
  uint32_t ow[12];
#pragma unroll
  for (int i = 0; i < 12; ++i) {
    int c0 = q * 24 + 2 * i;
    float v0 = (f[2 * i]     - mu) * rs * gamma[c0]     + beta[c0];
    float v1 = (f[2 * i + 1] - mu) * rs * gamma[c0 + 1] + beta[c0 + 1];
    ow[i] = (uint32_t)f2bf(v0) | ((uint32_t)f2bf(v1) << 16);
  }
  uint4* po = (uint4*)(xn + (size_t)vox * 96 + q * 24);
  po[0] = *(uint4*)&ow[0]; po[1] = *(uint4*)&ow[4]; po[2] = *(uint4*)&ow[8];
}

// ---------------- K2: repack qkv_w (fp32) into bf16 MFMA B-fragment layout ----------------
// Wb[tap][ks][nt][lane][j] : value = W[tap][ci=ks*32+(lane>>4)*8+j][co=nt*16+(lane&15)]
__global__ __launch_bounds__(256) void k_repack(const float* __restrict__ qw,
                                                u16* __restrict__ Wb) {
  int t = blockIdx.x * 256 + threadIdx.x;
  if (t >= 27 * 3 * 18 * 64) return;
  int l = t & 63;
  int rest = t >> 6;
  int nt = rest % 18;
  int ks = (rest / 18) % 3;
  int tap = rest / 54;
  int co = nt * 16 + (l & 15);
  int cibase = ks * 32 + (l >> 4) * 8;
  u16 vals[8];
#pragma unroll
  for (int j = 0; j < 8; ++j)
    vals[j] = f2bf(qw[((size_t)tap * 96 + cibase + j) * 288 + co]);
  *(uint4*)(Wb + (size_t)t * 8) = *(uint4*)vals;
}

// ---------------- K3: conv3d 3x3x3 96->288 via MFMA bf16 (R5 proven: 362us) ----------------
// Block = TWO adjacent z-columns (128 rows), 4 waves; wave = 1 column x 144 cols.
// A: double-buffered LDS, staged direct global->LDS once per dxy.
// B: register-rotated 1-deep pipeline (loads issued inside MFMA loop).
// NOTE (R6/R7 lesson): ANY extra staging array (sreg[7], bn[9]) spills to
// scratch (+240..780 MB traffic). Do not add register buffers here.
__global__ __launch_bounds__(256, 2) void k_conv(const u16* __restrict__ xn,
                                                 const u16* __restrict__ Wb,
                                                 const float* __restrict__ qkvb,
                                                 u16* __restrict__ y) {
  __shared__ u16 As[2][2 * 66 * 104];  // 54,912 B; pitch 104 (2-way benign)
  int tid = threadIdx.x;
  // bijective XCD swizzle: 2048 blocks, 8 XCDs, 256 blocks/XCD.
  int bid = blockIdx.x;
  int swz = (bid & 7) * 256 + (bid >> 3);
  int x0 = swz >> 5;
  int y0 = (swz & 31) * 2;
  int lane = tid & 63, w = tid >> 6;
  int wcol = w >> 1, wc = w & 1;

  f32x4 acc[4][9];
#pragma unroll
  for (int m = 0; m < 4; ++m)
#pragma unroll
    for (int n = 0; n < 9; ++n) acc[m][n] = (f32x4)0.f;

  const u16* wbase = Wb + (size_t)(wc * 9) * 512 + (size_t)lane * 8;

#define STAGE_A(DXY, BUF)                                                      \
  {                                                                            \
    int dx_ = (DXY) / 3, dy_ = (DXY) % 3;                                      \
    int xx_ = x0 + dx_ - 1;                                                    \
    for (int i = tid; i < 2 * 66 * 12; i += 256) {                             \
      int c_ = i / 792, rem_ = i - c_ * 792;                                   \
      int row_ = rem_ / 12, c8_ = rem_ - row_ * 12;                            \
      int yy_ = y0 + c_ + dy_ - 1;                                             \
      uint4 v_ = make_uint4(0u, 0u, 0u, 0u);                                   \
      if (((unsigned)xx_ < 64u) && ((unsigned)yy_ < 64u) && row_ >= 1 &&       \
          row_ <= 64) {                                                        \
        const uint4* src_ = (const uint4*)(xn + ((size_t)(xx_ * 64 + yy_) * 64) * 96); \
        v_ = src_[(row_ - 1) * 12 + c8_];                                      \
      }                                                                        \
      *(uint4*)&As[BUF][(c_ * 66 + row_) * 104 + c8_ * 8] = v_;                \
    }                                                                          \
  }

  STAGE_A(0, 0);
  __syncthreads();

  // preload B for (dxy=0, t=0)
  v8bf b[9];
#pragma unroll
  for (int nt = 0; nt < 9; ++nt)
    b[nt] = *(const v8bf*)(wbase + (size_t)nt * 512);

  for (int dxy = 0; dxy < 9; ++dxy) {
    const u16* Ab = &As[dxy & 1][0];
    const u16* base2 = wbase + (size_t)dxy * 9 * 9216;
    bool last_dxy = (dxy == 8);

#pragma unroll
    for (int t = 0; t < 9; ++t) {
      int dz = t / 3, ks = t - dz * 3;
      int ar = (lane & 15) + dz;
      int ac = ks * 32 + (lane >> 4) * 8;
      const u16* abase = &Ab[(wcol * 66 + ar) * 104 + ac];
      v8bf a0 = *(const v8bf*)(abase);
      v8bf a1 = *(const v8bf*)(abase + 16 * 104);
      v8bf a2 = *(const v8bf*)(abase + 32 * 104);
      v8bf a3 = *(const v8bf*)(abase + 48 * 104);
      const u16* bnxt = base2 + (size_t)(t + 1) * 9216;
      bool more = (t < 8) || !last_dxy;
      __builtin_amdgcn_s_setprio(1);
#pragma unroll
      for (int nt = 0; nt < 9; ++nt) {
        v8bf bb = b[nt];
        acc[0][nt] = __builtin_amdgcn_mfma_f32_16x16x32_bf16(a0, bb, acc[0][nt], 0, 0, 0);
        acc[1][nt] = __builtin_amdgcn_mfma_f32_16x16x32_bf16(a1, bb, acc[1][nt], 0, 0, 0);
        acc[2][nt] = __builtin_amdgcn_mfma_f32_16x16x32_bf16(a2, bb, acc[2][nt], 0, 0, 0);
        acc[3][nt] = __builtin_amdgcn_mfma_f32_16x16x32_bf16(a3, bb, acc[3][nt], 0, 0, 0);
        if (more) b[nt] = *(const v8bf*)(bnxt + (size_t)nt * 512);
      }
      __builtin_amdgcn_s_setprio(0);
    }

    if (!last_dxy) STAGE_A(dxy + 1, (dxy + 1) & 1);
    __syncthreads();
  }
#undef STAGE_A

  size_t voxbase = ((size_t)x0 * 64 + (y0 + wcol)) * 64;
#pragma unroll
  for (int m = 0; m < 4; ++m)
#pragma unroll
    for (int nt = 0; nt < 9; ++nt) {
      int co = wc * 144 + nt * 16 + (lane & 15);
      float bias = qkvb[co];
#pragma unroll
      for (int r = 0; r < 4; ++r) {
        int vrow = m * 16 + (lane >> 4) * 4 + r;
        y[(voxbase + vrow) * 288 + co] = f2bf(acc[m][nt][r] + bias);
      }
    }
}

// ---------------- K4: Gram via MFMA 32x32x16 ----------------
__global__ __launch_bounds__(256) void k_gram2(const u16* __restrict__ y,
                                               float* __restrict__ S_part,
                                               float* __restrict__ qn_part,
                                               float* __restrict__ kn_part) {
  __shared__ u16 buf[2][16 * 292];
  int tid = threadIdx.x;
  int f = blockIdx.x >> 4, chunk = blockIdx.x & 15;
  int fx = f >> 4, fy = (f >> 2) & 3, fz = f & 3;
  int l = tid & 63, h = tid >> 6;

  f32x16 aqk = (f32x16)0.f, aqq = (f32x16)0.f, akk = (f32x16)0.f;

  int i0 = tid;
  int gl0 = i0 / 24, c80 = i0 - gl0 * 24;
  int c00 = c80 * 8;
  int dst0 = (c00 < 96) ? ((c00 / 24) * 32 + (c00 % 24))
                        : (128 + ((c00 - 96) / 24) * 32 + ((c00 - 96) % 24));
  int i1 = tid + 256;
  int gl1 = i1 / 24, c81 = i1 - gl1 * 24;
  int c01 = c81 * 8;
  int dst1 = (c01 < 96) ? ((c01 / 24) * 32 + (c01 % 24))
                        : (128 + ((c01 - 96) / 24) * 32 + ((c01 - 96) % 24));
  bool has1 = (tid < 128);

  uint4 s0, s1;
  auto gload = [&](int sub) {
    int gbase = chunk * 256 + sub * 16;
    {
      int g = gbase + gl0;
      int gx = g >> 8, gy = (g >> 4) & 15, gz = g & 15;
      size_t vox = ((size_t)(gx * 4 + fx) * 64 + (gy * 4 + fy)) * 64 + (gz * 4 + fz);
      s0 = *(const uint4*)(y + vox * 288 + c00);
    }
    if (has1) {
      int g = gbase + gl1;
      int gx = g >> 8, gy = (g >> 4) & 15, gz = g & 15;
      size_t vox = ((size_t)(gx * 4 + fx) * 64 + (gy * 4 + fy)) * 64 + (gz * 4 + fz);
      s1 = *(const uint4*)(y + vox * 288 + c01);
    }
  };
  auto gwrite = [&](int bufi) {
    u16* p0 = &buf[bufi][gl0 * 292 + dst0];
    *(uint2*)p0 = make_uint2(s0.x, s0.y);
    *(uint2*)(p0 + 4) = make_uint2(s0.z, s0.w);
    if (has1) {
      u16* p1 = &buf[bufi][gl1 * 292 + dst1];
      *(uint2*)p1 = make_uint2(s1.x, s1.y);
      *(uint2*)(p1 + 4) = make_uint2(s1.z, s1.w);
    }
  };

  gload(0);
  gwrite(0);
  __syncthreads();

  for (int sub = 0; sub < 16; ++sub) {
    if (sub < 15) gload(sub + 1);  // issue next-tile loads early
    const u16* bb = &buf[sub & 1][(l >> 5) * 8 * 292 + h * 32 + (l & 31)];
    v8bf aq, ak;
#pragma unroll
    for (int j = 0; j < 8; ++j) {
      ((u16*)&aq)[j] = bb[j * 292];
      ((u16*)&ak)[j] = bb[j * 292 + 128];
    }
    aqk = __builtin_amdgcn_mfma_f32_32x32x16_bf16(aq, ak, aqk, 0, 0, 0);
    aqq = __builtin_amdgcn_mfma_f32_32x32x16_bf16(aq, aq, aqq, 0, 0, 0);
    akk = __builtin_amdgcn_mfma_f32_32x32x16_bf16(ak, ak, akk, 0, 0, 0);
    if (sub < 15) gwrite((sub + 1) & 1);
    __syncthreads();
  }

  int col = l & 31, hi = l >> 5;
  if (col < 24) {
    float* Sp = S_part + (((size_t)(chunk * 64 + f)) * 4 + h) * 576;
#pragma unroll
    for (int reg = 0; reg < 12; ++reg) {
      int row = (reg & 3) + 8 * (reg >> 2) + 4 * hi;
      Sp[row * 24 + col] = aqk[reg];
    }
    int sel = (col & 7) - 4 * hi;
    if (sel >= 0 && sel < 4) {
      int dreg = (col >> 3) * 4 + sel;
      float qn = 0.f, kn = 0.f;
#pragma unroll
      for (int r = 0; r < 12; ++r)
        if (r == dreg) { qn = aqq[r]; kn = akk[r]; }
      qn_part[((size_t)(chunk * 64 + f)) * 96 + h * 24 + col] = qn;
      kn_part[((size_t)(chunk * 64 + f)) * 96 + h * 24 + col] = kn;
    }
  }
}

// ---------------- K5: sum partials + softmax + fold out_w -> Mtf (B-frag layout) ----------------
// Mtf[f][ks][nt][lane][e] = Mt[f][j=ks*32+(lane>>4)*8+e][cp=nt*16+(lane&15)]
__global__ __launch_bounds__(256) void k_attn(const float* __restrict__ S_part,
                                              const float* __restrict__ qn_part,
                                              const float* __restrict__ kn_part,
                                              const float* __restrict__ out_w,
                                              const float* __restrict__ temp,
                                              u16* __restrict__ Mtf) {
  __shared__ float Ssum[2304];
  __shared__ float attn[2304];
  __shared__ float invq[96], invk[96];
  __shared__ float ow[9216];
  int tid = threadIdx.x;
  int f = blockIdx.x;
  for (int o = tid; o < 2304; o += 256) {
    float s = 0.f;
#pragma unroll
    for (int c = 0; c < 16; ++c) s += S_part[((size_t)(c * 64 + f)) * 2304 + o];
    Ssum[o] = s;
  }
  if (tid < 96) {
    float qn = 0.f, kn = 0.f;
#pragma unroll
    for (int c = 0; c < 16; ++c) {
      qn += qn_part[((size_t)(c * 64 + f)) * 96 + tid];
      kn += kn_part[((size_t)(c * 64 + f)) * 96 + tid];
    }
    invq[tid] = 1.f / fmaxf(sqrtf(qn), 1e-12f);
    invk[tid] = 1.f / fmaxf(sqrtf(kn), 1e-12f);
  }
  for (int i = tid; i < 9216; i += 256) ow[i] = out_w[i];
  __syncthreads();
  if (tid < 96) {
    int h = tid / 24, c = tid % 24;
    float tmp = temp[h];
    const float* Sr = &Ssum[h * 576 + c * 24];
    float lg[24];
    float mx = -1e30f;
#pragma unroll
    for (int d = 0; d < 24; ++d) {
      lg[d] = Sr[d] * invq[tid] * invk[h * 24 + d] * tmp;
      mx = fmaxf(mx, lg[d]);
    }
    float sum = 0.f;
#pragma unroll
    for (int d = 0; d < 24; ++d) { lg[d] = __expf(lg[d] - mx); sum += lg[d]; }
    float inv = 1.f / sum;
#pragma unroll
    for (int d = 0; d < 24; ++d) attn[h * 576 + c * 24 + d] = lg[d] * inv;
  }
  __syncthreads();
  for (int o = tid; o < 9216; o += 256) {
    int j = o / 96, cp = o - j * 96;
    int h2 = j / 24, d = j % 24;
    float s = 0.f;
#pragma unroll
    for (int cc = 0; cc < 24; ++cc)
      s += attn[h2 * 576 + cc * 24 + d] * ow[cp * 96 + h2 * 24 + cc];
    // write in B-fragment layout
    int ks = j >> 5, rem = j & 31;
    int lane = ((rem >> 3) << 4) + (cp & 15);
    int nt = cp >> 4, e = rem & 7;
    Mtf[(((size_t)f * 18 + ks * 6 + nt) * 64 + lane) * 8 + e] = f2bf(s);
  }
}

// ---------------- K6: out = Mt[f] @ v + out_b + x (residual) via MFMA ----------------
// Block = one z-column (64 vox), 4 waves; wave w handles fz=w group (16 vox):
// [16 vox x 96 j] @ Mt[f(x,y,w)][96 j x 96 cp]. v staged in LDS [fz][16][104]
// (row stride 208B -> 2-way banking, free). B-frags read direct from global
// (Mtf 1.2 MB, L2-hot — conv-proven pattern).
__global__ __launch_bounds__(256) void k_final2(const u16* __restrict__ y,
                                                const u16* __restrict__ Mtf,
                                                const float* __restrict__ xin,
                                                const float* __restrict__ out_b,
                                                float* __restrict__ out) {
  __shared__ u16 vst[4 * 16 * 104];  // 13,312 B
  int tid = threadIdx.x;
  int b = blockIdx.x;
  int x = b >> 6, yy = b & 63;
  size_t colvox = ((size_t)x * 64 + yy) * 64;
  int l = tid & 63, w = tid >> 6;
  int fx = x & 3, fy = yy & 3;
  const u16* mtb = Mtf + ((size_t)(fx * 16 + fy * 4 + w) * 18) * 512 + (size_t)l * 8;

  // stage v (y channels 192..287) into [fz][i][104]
  for (int i = tid; i < 768; i += 256) {
    int vv = i / 12, c8 = i - vv * 12;
    *(uint4*)&vst[((vv & 3) * 16 + (vv >> 2)) * 104 + c8 * 8] =
        *(const uint4*)(y + (colvox + vv) * 288 + 192 + c8 * 8);
  }
  __syncthreads();

  f32x4 acc[6];
#pragma unroll
  for (int nt = 0; nt < 6; ++nt) acc[nt] = (f32x4)0.f;

#pragma unroll
  for (int ks = 0; ks < 3; ++ks) {
    v8bf a = *(const v8bf*)&vst[(w * 16 + (l & 15)) * 104 + ks * 32 + (l >> 4) * 8];
#pragma unroll
    for (int nt = 0; nt < 6; ++nt) {
      v8bf bb = *(const v8bf*)(mtb + (size_t)(ks * 6 + nt) * 512);
      acc[nt] = __builtin_amdgcn_mfma_f32_16x16x32_bf16(a, bb, acc[nt], 0, 0, 0);
    }
  }

  // epilogue: + out_b + residual x, fp32 out
#pragma unroll
  for (int nt = 0; nt < 6; ++nt) {
    int cp = nt * 16 + (l & 15);
    float ob = out_b[cp];
#pragma unroll
    for (int r = 0; r < 4; ++r) {
      int vox = w + 4 * ((l >> 4) * 4 + r);
      size_t idx = (colvox + vox) * 96 + cp;
      out[idx] = acc[nt][r] + ob + xin[idx];
    }
  }
}

extern "C" void kernel_launch(void* const* d_in, const int* in_sizes, int n_in,
                              void* d_out, int out_size, void* d_ws, size_t ws_size,
                              hipStream_t stream) {
  const float* x  = (const float*)d_in[0];
  const float* g  = (const float*)d_in[1];
  const float* be = (const float*)d_in[2];
  const float* qw = (const float*)d_in[3];
  const float* qb = (const float*)d_in[4];
  const float* ow = (const float*)d_in[5];
  const float* ob = (const float*)d_in[6];
  const float* tp = (const float*)d_in[7];
  float* out = (float*)d_out;

  // d_out (100.7 MB) doubles as scratch until k_final2 overwrites it:
  //   xn (bf16, 50.3 MB) dead after k_conv; S/qn/kn partials dead after k_attn.
  u16* xn = (u16*)d_out;
  float* S_part  = (float*)((char*)d_out + 50331648);  // 9,437,184 B
  float* qn_part = (float*)((char*)d_out + 59768832);  //   393,216 B
  float* kn_part = (float*)((char*)d_out + 60162048);  //   393,216 B

  char* w = (char*)d_ws;
  u16* y   = (u16*)(w);                 // 150,994,944 B
  u16* Wb  = (u16*)(w + 150994944);     //   1,492,992 B
  u16* Mtf = (u16*)(w + 152487936);     //   1,179,648 B (end ~153.7 MB)

  hipLaunchKernelGGL(k_ln, dim3(4096), dim3(256), 0, stream, x, g, be, xn);
  hipLaunchKernelGGL(k_repack, dim3((27 * 3 * 18 * 64 + 255) / 256), dim3(256), 0, stream, qw, Wb);
  hipLaunchKernelGGL(k_conv, dim3(2048), dim3(256), 0, stream, xn, Wb, qb, y);
  hipLaunchKernelGGL(k_gram2, dim3(1024), dim3(256), 0, stream, y, S_part, qn_part, kn_part);
  hipLaunchKernelGGL(k_attn, dim3(64), dim3(256), 0, stream, S_part, qn_part, kn_part, ow, tp, Mtf);
  hipLaunchKernelGGL(k_final2, dim3(4096), dim3(256), 0, stream, y, Mtf, x, ob, out);
}

// Round 9
// 452.629 us; speedup vs baseline: 1.8552x; 1.0533x over previous
//
#include <hip/hip_runtime.h>
#include <stdint.h>

typedef unsigned short u16;
typedef float f32x4 __attribute__((ext_vector_type(4)));
typedef float f32x16 __attribute__((ext_vector_type(16)));
typedef __bf16 v8bf __attribute__((ext_vector_type(8)));

static __device__ __forceinline__ float bf2f(u16 u) {
  union { uint32_t i; float f; } v; v.i = ((uint32_t)u) << 16; return v.f;
}
static __device__ __forceinline__ u16 f2bf(float f) {
  union { float f; uint32_t i; } v; v.f = f;
  uint32_t b = v.i;
  return (u16)((b + 0x7FFFu + ((b >> 16) & 1u)) >> 16);
}

// ---------------- K1: LayerNorm over C=96 (fp32 in) -> bf16 xn ----------------
__global__ __launch_bounds__(256) void k_ln(const float* __restrict__ x,
                                            const float* __restrict__ gamma,
                                            const float* __restrict__ beta,
                                            u16* __restrict__ xn) {
  int tid = threadIdx.x;
  int vox = blockIdx.x * 64 + (tid >> 2);
  int q = tid & 3;
  const float4* px = (const float4*)(x + (size_t)vox * 96 + q * 24);
  float f[24];
  *(float4*)&f[0]  = px[0]; *(float4*)&f[4]  = px[1]; *(float4*)&f[8]  = px[2];
  *(float4*)&f[12] = px[3]; *(float4*)&f[16] = px[4]; *(float4*)&f[20] = px[5];
  float s = 0.f, s2 = 0.f;
#pragma unroll
  for (int i = 0; i < 24; ++i) { s += f[i]; s2 += f[i] * f[i]; }
  s += __shfl_xor(s, 1);  s += __shfl_xor(s, 2);
  s2 += __shfl_xor(s2, 1); s2 += __shfl_xor(s2, 2);
  float mu = s * (1.f / 96.f);
  float var = s2 * (1.f / 96.f) - mu * mu;
  float rs = rsqrtf(var + 1e-5f);
  uint32_t ow[12];
#pragma unroll
  for (int i = 0; i < 12; ++i) {
    int c0 = q * 24 + 2 * i;
    float v0 = (f[2 * i]     - mu) * rs * gamma[c0]     + beta[c0];
    float v1 = (f[2 * i + 1] - mu) * rs * gamma[c0 + 1] + beta[c0 + 1];
    ow[i] = (uint32_t)f2bf(v0) | ((uint32_t)f2bf(v1) << 16);
  }
  uint4* po = (uint4*)(xn + (size_t)vox * 96 + q * 24);
  po[0] = *(uint4*)&ow[0]; po[1] = *(uint4*)&ow[4]; po[2] = *(uint4*)&ow[8];
}

// ---------------- K2: repack qkv_w (fp32) into bf16 MFMA B-fragment layout ----------------
// Wb[tap][ks][nt][lane][j] : value = W[tap][ci=ks*32+(lane>>4)*8+j][co=nt*16+(lane&15)]
__global__ __launch_bounds__(256) void k_repack(const float* __restrict__ qw,
                                                u16* __restrict__ Wb) {
  int t = blockIdx.x * 256 + threadIdx.x;
  if (t >= 27 * 3 * 18 * 64) return;
  int l = t & 63;
  int rest = t >> 6;
  int nt = rest % 18;
  int ks = (rest / 18) % 3;
  int tap = rest / 54;
  int co = nt * 16 + (l & 15);
  int cibase = ks * 32 + (l >> 4) * 8;
  u16 vals[8];
#pragma unroll
  for (int j = 0; j < 8; ++j)
    vals[j] = f2bf(qw[((size_t)tap * 96 + cibase + j) * 288 + co]);
  *(uint4*)(Wb + (size_t)t * 8) = *(uint4*)vals;
}

// ---------------- K3: conv3d 3x3x3 96->288 via MFMA bf16 ----------------
// Block = TWO adjacent z-columns, 4 waves; wave = 1 column x 144 cols.
// R9 restructure: stage per-dx (ALL 4 y-columns y0-1..y0+2, 54.9 KB) instead
// of per-dxy -> 3 stages/block (vs 9), zero redundant column loads (12 vs 36),
// 6 barriers (vs 9), 27 t-steps (972 MFMAs) per stage window.
// B: register-rotated 1-deep pipeline, proven spill-free. NO extra reg arrays
// (R6/R7: any added staging array spills -> +240..780 MB scratch traffic).
__global__ __launch_bounds__(256, 2) void k_conv(const u16* __restrict__ xn,
                                                 const u16* __restrict__ Wb,
                                                 const float* __restrict__ qkvb,
                                                 u16* __restrict__ y) {
  __shared__ u16 As[4 * 66 * 104];  // 54,912 B; pitch 104 (2-way benign)
  int tid = threadIdx.x;
  // bijective XCD swizzle: 2048 blocks, 8 XCDs, 256 blocks/XCD.
  int bid = blockIdx.x;
  int swz = (bid & 7) * 256 + (bid >> 3);
  int x0 = swz >> 5;
  int y0 = (swz & 31) * 2;
  int lane = tid & 63, w = tid >> 6;
  int wcol = w >> 1, wc = w & 1;

  f32x4 acc[4][9];
#pragma unroll
  for (int m = 0; m < 4; ++m)
#pragma unroll
    for (int n = 0; n < 9; ++n) acc[m][n] = (f32x4)0.f;

  const u16* wbase = Wb + (size_t)(wc * 9) * 512 + (size_t)lane * 8;

  // stage all 4 halo columns (y0-1..y0+2) of x-plane xx = x0+DX-1
#define STAGE_A(DX)                                                            \
  {                                                                            \
    int xx_ = x0 + (DX) - 1;                                                   \
    for (int i = tid; i < 4 * 66 * 12; i += 256) {                             \
      int c_ = i / 792, rem_ = i - c_ * 792;                                   \
      int row_ = rem_ / 12, c8_ = rem_ - row_ * 12;                            \
      int yy_ = y0 + c_ - 1;                                                   \
      uint4 v_ = make_uint4(0u, 0u, 0u, 0u);                                   \
      if (((unsigned)xx_ < 64u) && ((unsigned)yy_ < 64u) && row_ >= 1 &&       \
          row_ <= 64) {                                                        \
        const uint4* src_ = (const uint4*)(xn + ((size_t)(xx_ * 64 + yy_) * 64) * 96); \
        v_ = src_[(row_ - 1) * 12 + c8_];                                      \
      }                                                                        \
      *(uint4*)&As[(c_ * 66 + row_) * 104 + c8_ * 8] = v_;                     \
    }                                                                          \
  }

  STAGE_A(0);

  // preload B for (tap=0, ks=0) while the first stage settles
  v8bf b[9];
#pragma unroll
  for (int nt = 0; nt < 9; ++nt)
    b[nt] = *(const v8bf*)(wbase + (size_t)nt * 512);

  __syncthreads();

  for (int dx = 0; dx < 3; ++dx) {
    const u16* base2 = wbase + (size_t)dx * 27 * 9216;
    bool last_dx = (dx == 2);

#pragma unroll
    for (int t2 = 0; t2 < 27; ++t2) {
      int dy = t2 / 9, rem9 = t2 - dy * 9;
      int dz = rem9 / 3, ks = rem9 - dz * 3;
      int ar = (lane & 15) + dz;
      int ac = ks * 32 + (lane >> 4) * 8;
      const u16* abase = &As[((wcol + dy) * 66 + ar) * 104 + ac];
      v8bf a0 = *(const v8bf*)(abase);
      v8bf a1 = *(const v8bf*)(abase + 16 * 104);
      v8bf a2 = *(const v8bf*)(abase + 32 * 104);
      v8bf a3 = *(const v8bf*)(abase + 48 * 104);
      const u16* bnxt = base2 + (size_t)(t2 + 1) * 9216;
      bool more = (t2 < 26) || !last_dx;
      __builtin_amdgcn_s_setprio(1);
#pragma unroll
      for (int nt = 0; nt < 9; ++nt) {
        v8bf bb = b[nt];
        acc[0][nt] = __builtin_amdgcn_mfma_f32_16x16x32_bf16(a0, bb, acc[0][nt], 0, 0, 0);
        acc[1][nt] = __builtin_amdgcn_mfma_f32_16x16x32_bf16(a1, bb, acc[1][nt], 0, 0, 0);
        acc[2][nt] = __builtin_amdgcn_mfma_f32_16x16x32_bf16(a2, bb, acc[2][nt], 0, 0, 0);
        acc[3][nt] = __builtin_amdgcn_mfma_f32_16x16x32_bf16(a3, bb, acc[3][nt], 0, 0, 0);
        if (more) b[nt] = *(const v8bf*)(bnxt + (size_t)nt * 512);
      }
      __builtin_amdgcn_s_setprio(0);
    }

    if (!last_dx) {
      __syncthreads();      // all waves done reading As
      STAGE_A(dx + 1);      // overwrite with next x-plane
      __syncthreads();      // writes visible
    }
  }
#undef STAGE_A

  size_t voxbase = ((size_t)x0 * 64 + (y0 + wcol)) * 64;
#pragma unroll
  for (int m = 0; m < 4; ++m)
#pragma unroll
    for (int nt = 0; nt < 9; ++nt) {
      int co = wc * 144 + nt * 16 + (lane & 15);
      float bias = qkvb[co];
#pragma unroll
      for (int r = 0; r < 4; ++r) {
        int vrow = m * 16 + (lane >> 4) * 4 + r;
        y[(voxbase + vrow) * 288 + co] = f2bf(acc[m][nt][r] + bias);
      }
    }
}

// ---------------- K4: Gram via MFMA 32x32x16 ----------------
__global__ __launch_bounds__(256) void k_gram2(const u16* __restrict__ y,
                                               float* __restrict__ S_part,
                                               float* __restrict__ qn_part,
                                               float* __restrict__ kn_part) {
  __shared__ u16 buf[2][16 * 292];
  int tid = threadIdx.x;
  int f = blockIdx.x >> 4, chunk = blockIdx.x & 15;
  int fx = f >> 4, fy = (f >> 2) & 3, fz = f & 3;
  int l = tid & 63, h = tid >> 6;

  f32x16 aqk = (f32x16)0.f, aqq = (f32x16)0.f, akk = (f32x16)0.f;

  int i0 = tid;
  int gl0 = i0 / 24, c80 = i0 - gl0 * 24;
  int c00 = c80 * 8;
  int dst0 = (c00 < 96) ? ((c00 / 24) * 32 + (c00 % 24))
                        : (128 + ((c00 - 96) / 24) * 32 + ((c00 - 96) % 24));
  int i1 = tid + 256;
  int gl1 = i1 / 24, c81 = i1 - gl1 * 24;
  int c01 = c81 * 8;
  int dst1 = (c01 < 96) ? ((c01 / 24) * 32 + (c01 % 24))
                        : (128 + ((c01 - 96) / 24) * 32 + ((c01 - 96) % 24));
  bool has1 = (tid < 128);

  uint4 s0, s1;
  auto gload = [&](int sub) {
    int gbase = chunk * 256 + sub * 16;
    {
      int g = gbase + gl0;
      int gx = g >> 8, gy = (g >> 4) & 15, gz = g & 15;
      size_t vox = ((size_t)(gx * 4 + fx) * 64 + (gy * 4 + fy)) * 64 + (gz * 4 + fz);
      s0 = *(const uint4*)(y + vox * 288 + c00);
    }
    if (has1) {
      int g = gbase + gl1;
      int gx = g >> 8, gy = (g >> 4) & 15, gz = g & 15;
      size_t vox = ((size_t)(gx * 4 + fx) * 64 + (gy * 4 + fy)) * 64 + (gz * 4 + fz);
      s1 = *(const uint4*)(y + vox * 288 + c01);
    }
  };
  auto gwrite = [&](int bufi) {
    u16* p0 = &buf[bufi][gl0 * 292 + dst0];
    *(uint2*)p0 = make_uint2(s0.x, s0.y);
    *(uint2*)(p0 + 4) = make_uint2(s0.z, s0.w);
    if (has1) {
      u16* p1 = &buf[bufi][gl1 * 292 + dst1];
      *(uint2*)p1 = make_uint2(s1.x, s1.y);
      *(uint2*)(p1 + 4) = make_uint2(s1.z, s1.w);
    }
  };

  gload(0);
  gwrite(0);
  __syncthreads();

  for (int sub = 0; sub < 16; ++sub) {
    if (sub < 15) gload(sub + 1);  // issue next-tile loads early
    const u16* bb = &buf[sub & 1][(l >> 5) * 8 * 292 + h * 32 + (l & 31)];
    v8bf aq, ak;
#pragma unroll
    for (int j = 0; j < 8; ++j) {
      ((u16*)&aq)[j] = bb[j * 292];
      ((u16*)&ak)[j] = bb[j * 292 + 128];
    }
    aqk = __builtin_amdgcn_mfma_f32_32x32x16_bf16(aq, ak, aqk, 0, 0, 0);
    aqq = __builtin_amdgcn_mfma_f32_32x32x16_bf16(aq, aq, aqq, 0, 0, 0);
    akk = __builtin_amdgcn_mfma_f32_32x32x16_bf16(ak, ak, akk, 0, 0, 0);
    if (sub < 15) gwrite((sub + 1) & 1);
    __syncthreads();
  }

  int col = l & 31, hi = l >> 5;
  if (col < 24) {
    float* Sp = S_part + (((size_t)(chunk * 64 + f)) * 4 + h) * 576;
#pragma unroll
    for (int reg = 0; reg < 12; ++reg) {
      int row = (reg & 3) + 8 * (reg >> 2) + 4 * hi;
      Sp[row * 24 + col] = aqk[reg];
    }
    int sel = (col & 7) - 4 * hi;
    if (sel >= 0 && sel < 4) {
      int dreg = (col >> 3) * 4 + sel;
      float qn = 0.f, kn = 0.f;
#pragma unroll
      for (int r = 0; r < 12; ++r)
        if (r == dreg) { qn = aqq[r]; kn = akk[r]; }
      qn_part[((size_t)(chunk * 64 + f)) * 96 + h * 24 + col] = qn;
      kn_part[((size_t)(chunk * 64 + f)) * 96 + h * 24 + col] = kn;
    }
  }
}

// ---------------- K5: sum partials + softmax + fold out_w -> Mtf (B-frag layout) ----------------
// Mtf[f][ks][nt][lane][e] = Mt[f][j=ks*32+(lane>>4)*8+e][cp=nt*16+(lane&15)]
__global__ __launch_bounds__(256) void k_attn(const float* __restrict__ S_part,
                                              const float* __restrict__ qn_part,
                                              const float* __restrict__ kn_part,
                                              const float* __restrict__ out_w,
                                              const float* __restrict__ temp,
                                              u16* __restrict__ Mtf) {
  __shared__ float Ssum[2304];
  __shared__ float attn[2304];
  __shared__ float invq[96], invk[96];
  __shared__ float ow[9216];
  int tid = threadIdx.x;
  int f = blockIdx.x;
  for (int o = tid; o < 2304; o += 256) {
    float s = 0.f;
#pragma unroll
    for (int c = 0; c < 16; ++c) s += S_part[((size_t)(c * 64 + f)) * 2304 + o];
    Ssum[o] = s;
  }
  if (tid < 96) {
    float qn = 0.f, kn = 0.f;
#pragma unroll
    for (int c = 0; c < 16; ++c) {
      qn += qn_part[((size_t)(c * 64 + f)) * 96 + tid];
      kn += kn_part[((size_t)(c * 64 + f)) * 96 + tid];
    }
    invq[tid] = 1.f / fmaxf(sqrtf(qn), 1e-12f);
    invk[tid] = 1.f / fmaxf(sqrtf(kn), 1e-12f);
  }
  for (int i = tid; i < 9216; i += 256) ow[i] = out_w[i];
  __syncthreads();
  if (tid < 96) {
    int h = tid / 24, c = tid % 24;
    float tmp = temp[h];
    const float* Sr = &Ssum[h * 576 + c * 24];
    float lg[24];
    float mx = -1e30f;
#pragma unroll
    for (int d = 0; d < 24; ++d) {
      lg[d] = Sr[d] * invq[tid] * invk[h * 24 + d] * tmp;
      mx = fmaxf(mx, lg[d]);
    }
    float sum = 0.f;
#pragma unroll
    for (int d = 0; d < 24; ++d) { lg[d] = __expf(lg[d] - mx); sum += lg[d]; }
    float inv = 1.f / sum;
#pragma unroll
    for (int d = 0; d < 24; ++d) attn[h * 576 + c * 24 + d] = lg[d] * inv;
  }
  __syncthreads();
  for (int o = tid; o < 9216; o += 256) {
    int j = o / 96, cp = o - j * 96;
    int h2 = j / 24, d = j % 24;
    float s = 0.f;
#pragma unroll
    for (int cc = 0; cc < 24; ++cc)
      s += attn[h2 * 576 + cc * 24 + d] * ow[cp * 96 + h2 * 24 + cc];
    // write in B-fragment layout
    int ks = j >> 5, rem = j & 31;
    int lane = ((rem >> 3) << 4) + (cp & 15);
    int nt = cp >> 4, e = rem & 7;
    Mtf[(((size_t)f * 18 + ks * 6 + nt) * 64 + lane) * 8 + e] = f2bf(s);
  }
}

// ---------------- K6: out = Mt[f] @ v + out_b + x (residual) via MFMA ----------------
__global__ __launch_bounds__(256) void k_final2(const u16* __restrict__ y,
                                                const u16* __restrict__ Mtf,
                                                const float* __restrict__ xin,
                                                const float* __restrict__ out_b,
                                                float* __restrict__ out) {
  __shared__ u16 vst[4 * 16 * 104];  // 13,312 B
  int tid = threadIdx.x;
  int b = blockIdx.x;
  int x = b >> 6, yy = b & 63;
  size_t colvox = ((size_t)x * 64 + yy) * 64;
  int l = tid & 63, w = tid >> 6;
  int fx = x & 3, fy = yy & 3;
  const u16* mtb = Mtf + ((size_t)(fx * 16 + fy * 4 + w) * 18) * 512 + (size_t)l * 8;

  // stage v (y channels 192..287) into [fz][i][104]
  for (int i = tid; i < 768; i += 256) {
    int vv = i / 12, c8 = i - vv * 12;
    *(uint4*)&vst[((vv & 3) * 16 + (vv >> 2)) * 104 + c8 * 8] =
        *(const uint4*)(y + (colvox + vv) * 288 + 192 + c8 * 8);
  }
  __syncthreads();

  f32x4 acc[6];
#pragma unroll
  for (int nt = 0; nt < 6; ++nt) acc[nt] = (f32x4)0.f;

#pragma unroll
  for (int ks = 0; ks < 3; ++ks) {
    v8bf a = *(const v8bf*)&vst[(w * 16 + (l & 15)) * 104 + ks * 32 + (l >> 4) * 8];
#pragma unroll
    for (int nt = 0; nt < 6; ++nt) {
      v8bf bb = *(const v8bf*)(mtb + (size_t)(ks * 6 + nt) * 512);
      acc[nt] = __builtin_amdgcn_mfma_f32_16x16x32_bf16(a, bb, acc[nt], 0, 0, 0);
    }
  }

  // epilogue: + out_b + residual x, fp32 out
#pragma unroll
  for (int nt = 0; nt < 6; ++nt) {
    int cp = nt * 16 + (l & 15);
    float ob = out_b[cp];
#pragma unroll
    for (int r = 0; r < 4; ++r) {
      int vox = w + 4 * ((l >> 4) * 4 + r);
      size_t idx = (colvox + vox) * 96 + cp;
      out[idx] = acc[nt][r] + ob + xin[idx];
    }
  }
}

extern "C" void kernel_launch(void* const* d_in, const int* in_sizes, int n_in,
                              void* d_out, int out_size, void* d_ws, size_t ws_size,
                              hipStream_t stream) {
  const float* x  = (const float*)d_in[0];
  const float* g  = (const float*)d_in[1];
  const float* be = (const float*)d_in[2];
  const float* qw = (const float*)d_in[3];
  const float* qb = (const float*)d_in[4];
  const float* ow = (const float*)d_in[5];
  const float* ob = (const float*)d_in[6];
  const float* tp = (const float*)d_in[7];
  float* out = (float*)d_out;

  // d_out (100.7 MB) doubles as scratch until k_final2 overwrites it:
  //   xn (bf16, 50.3 MB) dead after k_conv; S/qn/kn partials dead after k_attn.
  u16* xn = (u16*)d_out;
  float* S_part  = (float*)((char*)d_out + 50331648);  // 9,437,184 B
  float* qn_part = (float*)((char*)d_out + 59768832);  //   393,216 B
  float* kn_part = (float*)((char*)d_out + 60162048);  //   393,216 B

  char* w = (char*)d_ws;
  u16* y   = (u16*)(w);                 // 150,994,944 B
  u16* Wb  = (u16*)(w + 150994944);     //   1,492,992 B
  u16* Mtf = (u16*)(w + 152487936);     //   1,179,648 B (end ~153.7 MB)

  hipLaunchKernelGGL(k_ln, dim3(4096), dim3(256), 0, stream, x, g, be, xn);
  hipLaunchKernelGGL(k_repack, dim3((27 * 3 * 18 * 64 + 255) / 256), dim3(256), 0, stream, qw, Wb);
  hipLaunchKernelGGL(k_conv, dim3(2048), dim3(256), 0, stream, xn, Wb, qb, y);
  hipLaunchKernelGGL(k_gram2, dim3(1024), dim3(256), 0, stream, y, S_part, qn_part, kn_part);
  hipLaunchKernelGGL(k_attn, dim3(64), dim3(256), 0, stream, S_part, qn_part, kn_part, ow, tp, Mtf);
  hipLaunchKernelGGL(k_final2, dim3(4096), dim3(256), 0, stream, y, Mtf, x, ob, out);
}